// Round 1
// baseline (727.673 us; speedup 1.0000x reference)
//
#include <hip/hip_runtime.h>
#include <hip/hip_bf16.h>

// Problem constants (shapes fixed by the reference)
#define FIN  128
#define HDIM 256

using bf16 = __hip_bfloat16;
using short8 = __attribute__((ext_vector_type(8))) short;
using f32x4  = __attribute__((ext_vector_type(4))) float;

// ---------------- CSR build ----------------

__global__ void k_count(const int* __restrict__ dst, int* __restrict__ deg, int E) {
    int e = blockIdx.x * blockDim.x + threadIdx.x;
    if (e < E) atomicAdd(&deg[dst[e]], 1);
}

__global__ void k_dinv(const int* __restrict__ deg, float* __restrict__ dinv, int N) {
    int n = blockIdx.x * blockDim.x + threadIdx.x;
    if (n < N) dinv[n] = rsqrtf((float)deg[n] + 1.0f);   // +1 self-loop
}

// single-block exclusive scan of deg -> row_ptr (and a working copy in cursor)
__global__ void k_scan(const int* __restrict__ deg, int* __restrict__ row_ptr,
                       int* __restrict__ cursor, int N, int E) {
    __shared__ int part[1024];
    int t = threadIdx.x;
    int chunk = (N + 1023) / 1024;
    int lo = t * chunk;
    int hi = lo + chunk; if (hi > N) hi = N;
    int s = 0;
    for (int i = lo; i < hi; ++i) s += deg[i];
    part[t] = s;
    __syncthreads();
    for (int off = 1; off < 1024; off <<= 1) {
        int v = (t >= off) ? part[t - off] : 0;
        __syncthreads();
        part[t] += v;
        __syncthreads();
    }
    int run = (t > 0) ? part[t - 1] : 0;
    for (int i = lo; i < hi; ++i) {
        row_ptr[i] = run; cursor[i] = run;
        run += deg[i];
    }
    if (t == 0) row_ptr[N] = E;
}

__global__ void k_fill(const int* __restrict__ src, const int* __restrict__ dst,
                       int* __restrict__ cursor, int* __restrict__ csr_src, int E) {
    int e = blockIdx.x * blockDim.x + threadIdx.x;
    if (e < E) {
        int pos = atomicAdd(&cursor[dst[e]], 1);
        csr_src[pos] = src[e];
    }
}

// ---------------- dtype conversion ----------------

__global__ void k_cvt(const float* __restrict__ in, bf16* __restrict__ out, int n) {
    int i = blockIdx.x * blockDim.x + threadIdx.x;
    if (i < n) out[i] = __float2bfloat16(in[i]);
}

// w[K][C] row-major -> wT[C][K] bf16 (B^T layout for MFMA B-fragments)
__global__ void k_cvt_wT(const float* __restrict__ w, bf16* __restrict__ wT, int K, int C) {
    int i = blockIdx.x * blockDim.x + threadIdx.x;
    if (i < K * C) {
        int k = i / C, c = i % C;
        wT[c * K + k] = __float2bfloat16(w[i]);
    }
}

// ---------------- GEMM: C[M,256] = A[M,K](bf16) * B[K,256], BT = B^T [256,K] ----------------
// Per-wave 16x64 output tile via 4x mfma_f32_16x16x32_bf16; frags loaded directly
// from global (16B/lane). A-frag: A[m=lane&15][k=quad*8+j]; B-frag: BT[n=lane&15][k=quad*8+j].
// C/D layout: col=lane&15, row=quad*4+reg (verified mapping).
// Requires M % 16 == 0 (holds: 50000 = 3125*16), K % 32 == 0, N == 256.

__global__ void k_gemm(const bf16* __restrict__ A, const bf16* __restrict__ BT,
                       float* __restrict__ C, int M, int K) {
    int wave = threadIdx.x >> 6;
    int lane = threadIdx.x & 63;
    int rowTile = blockIdx.x * 4 + wave;
    if (rowTile * 16 >= M) return;
    int m0 = rowTile * 16;
    int n0 = blockIdx.y * 64;
    int l15 = lane & 15, quad = lane >> 4;

    f32x4 acc0 = {0.f,0.f,0.f,0.f}, acc1 = {0.f,0.f,0.f,0.f};
    f32x4 acc2 = {0.f,0.f,0.f,0.f}, acc3 = {0.f,0.f,0.f,0.f};

    const short* Ap = (const short*)A + (size_t)(m0 + l15) * K + quad * 8;
    const short* B0 = (const short*)BT + (size_t)(n0 +  0 + l15) * K + quad * 8;
    const short* B1 = (const short*)BT + (size_t)(n0 + 16 + l15) * K + quad * 8;
    const short* B2 = (const short*)BT + (size_t)(n0 + 32 + l15) * K + quad * 8;
    const short* B3 = (const short*)BT + (size_t)(n0 + 48 + l15) * K + quad * 8;

    for (int k = 0; k < K; k += 32) {
        short8 a  = *(const short8*)(Ap + k);
        short8 b0 = *(const short8*)(B0 + k);
        short8 b1 = *(const short8*)(B1 + k);
        short8 b2 = *(const short8*)(B2 + k);
        short8 b3 = *(const short8*)(B3 + k);
        acc0 = __builtin_amdgcn_mfma_f32_16x16x32_bf16(a, b0, acc0, 0, 0, 0);
        acc1 = __builtin_amdgcn_mfma_f32_16x16x32_bf16(a, b1, acc1, 0, 0, 0);
        acc2 = __builtin_amdgcn_mfma_f32_16x16x32_bf16(a, b2, acc2, 0, 0, 0);
        acc3 = __builtin_amdgcn_mfma_f32_16x16x32_bf16(a, b3, acc3, 0, 0, 0);
    }

    float* Cp = C + (size_t)(m0 + quad * 4) * HDIM + n0 + l15;
    #pragma unroll
    for (int r = 0; r < 4; ++r) {
        Cp[(size_t)r * HDIM +  0] = acc0[r];
        Cp[(size_t)r * HDIM + 16] = acc1[r];
        Cp[(size_t)r * HDIM + 32] = acc2[r];
        Cp[(size_t)r * HDIM + 48] = acc3[r];
    }
}

// ---------------- Aggregation: one wave per dst node ----------------
// out[n] = relu( sum_{e: dst=n} dinv[src]*dinv[n]*hlin[src] + dinv[n]^2*hlin[n] + bias )
// lane covers cols 4*lane..4*lane+3 (float4 => wave reads a full 1KB row, coalesced).

__global__ void k_agg(const float* __restrict__ hlin, const float* __restrict__ dinv,
                      const int* __restrict__ row_ptr, const int* __restrict__ csr_src,
                      const float* __restrict__ bias,
                      bf16* __restrict__ outb, float* __restrict__ outf, int N) {
    int wave = threadIdx.x >> 6, lane = threadIdx.x & 63;
    int n = blockIdx.x * 4 + wave;
    if (n >= N) return;
    float dn = dinv[n];
    int beg = row_ptr[n], end = row_ptr[n + 1];
    int col = lane * 4;
    float ax = 0.f, ay = 0.f, az = 0.f, aw = 0.f;
    for (int j = beg; j < end; ++j) {
        int s = csr_src[j];
        float c = dinv[s] * dn;
        const float4 v = *(const float4*)(hlin + (size_t)s * HDIM + col);
        ax = fmaf(c, v.x, ax); ay = fmaf(c, v.y, ay);
        az = fmaf(c, v.z, az); aw = fmaf(c, v.w, aw);
    }
    const float4 sv = *(const float4*)(hlin + (size_t)n * HDIM + col);
    const float4 b4 = *(const float4*)(bias + col);
    float sc = dn * dn;
    float r0 = fmaxf(fmaf(sc, sv.x, ax) + b4.x, 0.f);
    float r1 = fmaxf(fmaf(sc, sv.y, ay) + b4.y, 0.f);
    float r2 = fmaxf(fmaf(sc, sv.z, az) + b4.z, 0.f);
    float r3 = fmaxf(fmaf(sc, sv.w, aw) + b4.w, 0.f);
    if (outb) {
        bf16 t0 = __float2bfloat16(r0), t1 = __float2bfloat16(r1);
        bf16 t2 = __float2bfloat16(r2), t3 = __float2bfloat16(r3);
        ushort4 p;
        p.x = *(unsigned short*)&t0; p.y = *(unsigned short*)&t1;
        p.z = *(unsigned short*)&t2; p.w = *(unsigned short*)&t3;
        *(ushort4*)(outb + (size_t)n * HDIM + col) = p;
    } else {
        *(float4*)(outf + (size_t)n * HDIM + col) = make_float4(r0, r1, r2, r3);
    }
}

// ---------------- mean-pool partials + final linear ----------------

__global__ void k_colsum(const float* __restrict__ h2, float* __restrict__ gsum, int N) {
    int c = threadIdx.x;  // 256
    float acc = 0.f;
    for (int r = blockIdx.x; r < N; r += gridDim.x)
        acc += h2[(size_t)r * HDIM + c];
    atomicAdd(&gsum[c], acc);
}

__global__ void k_final(const float* __restrict__ gsum, const float* __restrict__ Wl,
                        const float* __restrict__ bl, float* __restrict__ out, float invN) {
    __shared__ float s0[256], s1[256];
    int c = threadIdx.x;
    float g = gsum[c] * invN;
    s0[c] = g * Wl[c * 2 + 0];
    s1[c] = g * Wl[c * 2 + 1];
    __syncthreads();
    for (int off = 128; off > 0; off >>= 1) {
        if (c < off) { s0[c] += s0[c + off]; s1[c] += s1[c + off]; }
        __syncthreads();
    }
    if (c == 0) { out[0] = s0[0] + bl[0]; out[1] = s1[0] + bl[1]; }
}

// ---------------- launch ----------------

extern "C" void kernel_launch(void* const* d_in, const int* in_sizes, int n_in,
                              void* d_out, int out_size, void* d_ws, size_t ws_size,
                              hipStream_t stream) {
    const float* x  = (const float*)d_in[0];
    const int*   ei = (const int*)d_in[1];
    // d_in[2] = batch (unused, all zeros)
    const float* W1 = (const float*)d_in[3];
    const float* b1 = (const float*)d_in[4];
    const float* W2 = (const float*)d_in[5];
    const float* b2 = (const float*)d_in[6];
    const float* Wl = (const float*)d_in[7];
    const float* bl = (const float*)d_in[8];
    float* out = (float*)d_out;

    const int N = in_sizes[0] / FIN;   // 50000
    const int E = in_sizes[1] / 2;     // 800000
    const int* src = ei;
    const int* dst = ei + E;

    // workspace carve-up (256B aligned). Total ~145 MB.
    char* ws = (char*)d_ws;
    size_t off = 0;
    auto alloc = [&](size_t bytes) -> void* {
        void* p = ws + off;
        off = (off + bytes + 255) & ~(size_t)255;
        return p;
    };
    int*   deg     = (int*)  alloc((size_t)N * 4);
    float* dinv    = (float*)alloc((size_t)N * 4);
    int*   row_ptr = (int*)  alloc((size_t)(N + 1) * 4);
    int*   cursor  = (int*)  alloc((size_t)N * 4);
    int*   csr_src = (int*)  alloc((size_t)E * 4);
    bf16*  Xb      = (bf16*) alloc((size_t)N * FIN * 2);
    bf16*  W1T     = (bf16*) alloc((size_t)FIN * HDIM * 2);
    bf16*  W2T     = (bf16*) alloc((size_t)HDIM * HDIM * 2);
    float* hlin    = (float*)alloc((size_t)N * HDIM * 4);   // reused both layers
    bf16*  h1b     = (bf16*) alloc((size_t)N * HDIM * 2);
    float* h2      = (float*)alloc((size_t)N * HDIM * 4);
    float* gsum    = (float*)alloc((size_t)HDIM * 4);

    hipMemsetAsync(deg, 0, (size_t)N * 4, stream);
    hipMemsetAsync(gsum, 0, (size_t)HDIM * 4, stream);

    // CSR build (by dst)
    k_count<<<(E + 255) / 256, 256, 0, stream>>>(dst, deg, E);
    k_dinv <<<(N + 255) / 256, 256, 0, stream>>>(deg, dinv, N);
    k_scan <<<1, 1024, 0, stream>>>(deg, row_ptr, cursor, N, E);
    k_fill <<<(E + 255) / 256, 256, 0, stream>>>(src, dst, cursor, csr_src, E);

    // bf16 casts
    k_cvt   <<<((size_t)N * FIN + 255) / 256, 256, 0, stream>>>(x, Xb, N * FIN);
    k_cvt_wT<<<(FIN * HDIM + 255) / 256, 256, 0, stream>>>(W1, W1T, FIN, HDIM);
    k_cvt_wT<<<(HDIM * HDIM + 255) / 256, 256, 0, stream>>>(W2, W2T, HDIM, HDIM);

    dim3 gemm_grid((N / 16 + 3) / 4, HDIM / 64);

    // layer 1
    k_gemm<<<gemm_grid, 256, 0, stream>>>(Xb, W1T, hlin, N, FIN);
    k_agg <<<(N + 3) / 4, 256, 0, stream>>>(hlin, dinv, row_ptr, csr_src, b1, h1b, nullptr, N);

    // layer 2
    k_gemm<<<gemm_grid, 256, 0, stream>>>(h1b, W2T, hlin, N, HDIM);
    k_agg <<<(N + 3) / 4, 256, 0, stream>>>(hlin, dinv, row_ptr, csr_src, b2, nullptr, h2, N);

    // mean-pool + final linear
    k_colsum<<<128, 256, 0, stream>>>(h2, gsum, N);
    k_final <<<1, 256, 0, stream>>>(gsum, Wl, bl, out, 1.0f / (float)N);
}

// Round 2
// 448.310 us; speedup vs baseline: 1.6231x; 1.6231x over previous
//
#include <hip/hip_runtime.h>
#include <hip/hip_bf16.h>

#define FIN  128
#define HDIM 256

using bf16 = __hip_bfloat16;
using short8 = __attribute__((ext_vector_type(8))) short;
using f32x4  = __attribute__((ext_vector_type(4))) float;

static __device__ __forceinline__ unsigned short f2bu(float f) {
    bf16 t = __float2bfloat16(f);
    return *(unsigned short*)&t;
}
static __device__ __forceinline__ float b2f(unsigned short u) {
    return __uint_as_float(((unsigned)u) << 16);
}

// ---------------- CSR build ----------------

__global__ void k_count(const int* __restrict__ dst, int* __restrict__ deg, int E) {
    int e = blockIdx.x * blockDim.x + threadIdx.x;
    if (e < E) atomicAdd(&deg[dst[e]], 1);
}

// per-block sums of deg (256 elems per block)
__global__ void k_blocksum(const int* __restrict__ deg, int* __restrict__ bsum, int N) {
    __shared__ int s[256];
    int t = threadIdx.x;
    int i = blockIdx.x * 256 + t;
    s[t] = (i < N) ? deg[i] : 0;
    __syncthreads();
    for (int off = 128; off > 0; off >>= 1) {
        if (t < off) s[t] += s[t + off];
        __syncthreads();
    }
    if (t == 0) bsum[blockIdx.x] = s[0];
}

// single-block exclusive scan of block sums (NB <= 256)
__global__ void k_scanb(const int* __restrict__ bsum, int* __restrict__ boff, int NB) {
    __shared__ int s[256];
    int t = threadIdx.x;
    int v = (t < NB) ? bsum[t] : 0;
    s[t] = v;
    __syncthreads();
    for (int off = 1; off < 256; off <<= 1) {
        int u = (t >= off) ? s[t - off] : 0;
        __syncthreads();
        s[t] += u;
        __syncthreads();
    }
    if (t < NB) boff[t] = s[t] - v;   // exclusive
}

// per-block re-scan: write row_ptr + cursor, and dinv = rsqrt(deg+1)
__global__ void k_scatter(const int* __restrict__ deg, const int* __restrict__ boff,
                          int* __restrict__ row_ptr, int* __restrict__ cursor,
                          float* __restrict__ dinv, int N, int E) {
    __shared__ int s[256];
    int t = threadIdx.x;
    int i = blockIdx.x * 256 + t;
    int v = (i < N) ? deg[i] : 0;
    s[t] = v;
    __syncthreads();
    for (int off = 1; off < 256; off <<= 1) {
        int u = (t >= off) ? s[t - off] : 0;
        __syncthreads();
        s[t] += u;
        __syncthreads();
    }
    if (i < N) {
        int excl = boff[blockIdx.x] + s[t] - v;
        row_ptr[i] = excl;
        cursor[i]  = excl;
        dinv[i]    = rsqrtf((float)v + 1.0f);
    }
    if (blockIdx.x == 0 && t == 0) row_ptr[N] = E;
}

// fill CSR with (src, coef) pairs; coef = dinv[src]*dinv[dst]
__global__ void k_fill(const int* __restrict__ src, const int* __restrict__ dst,
                       const float* __restrict__ dinv,
                       int* __restrict__ cursor, int2* __restrict__ csr, int E) {
    int e = blockIdx.x * blockDim.x + threadIdx.x;
    if (e < E) {
        int s = src[e], d = dst[e];
        int pos = atomicAdd(&cursor[d], 1);
        float c = dinv[s] * dinv[d];
        csr[pos] = make_int2(s, __float_as_int(c));
    }
}

// ---------------- dtype conversion ----------------

__global__ void k_cvt(const float* __restrict__ in, unsigned short* __restrict__ out, int n) {
    int i = blockIdx.x * blockDim.x + threadIdx.x;
    if (i < n) out[i] = f2bu(in[i]);
}

// w[K][C] row-major -> wT[C][K] bf16
__global__ void k_cvt_wT(const float* __restrict__ w, unsigned short* __restrict__ wT, int K, int C) {
    int i = blockIdx.x * blockDim.x + threadIdx.x;
    if (i < K * C) {
        int k = i / C, c = i % C;
        wT[c * K + k] = f2bu(w[i]);
    }
}

// ---------------- GEMM: C[M,256](bf16) = A[M,K](bf16) * B[K,256], BT = B^T ----------------
// Per-wave 16x64 tile via 4x mfma_f32_16x16x32_bf16, frags direct from global.
// C/D layout: col=lane&15, row=quad*4+reg.

template <int K>
__global__ __launch_bounds__(256, 4) void k_gemm(const unsigned short* __restrict__ A,
                                                 const unsigned short* __restrict__ BT,
                                                 unsigned short* __restrict__ C, int M) {
    int wave = threadIdx.x >> 6;
    int lane = threadIdx.x & 63;
    int rowTile = blockIdx.x * 4 + wave;
    if (rowTile * 16 >= M) return;
    int m0 = rowTile * 16;
    int n0 = blockIdx.y * 64;
    int l15 = lane & 15, quad = lane >> 4;

    f32x4 acc0 = {0.f,0.f,0.f,0.f}, acc1 = {0.f,0.f,0.f,0.f};
    f32x4 acc2 = {0.f,0.f,0.f,0.f}, acc3 = {0.f,0.f,0.f,0.f};

    const short* Ap = (const short*)A + (size_t)(m0 + l15) * K + quad * 8;
    const short* B0 = (const short*)BT + (size_t)(n0 +  0 + l15) * K + quad * 8;
    const short* B1 = (const short*)BT + (size_t)(n0 + 16 + l15) * K + quad * 8;
    const short* B2 = (const short*)BT + (size_t)(n0 + 32 + l15) * K + quad * 8;
    const short* B3 = (const short*)BT + (size_t)(n0 + 48 + l15) * K + quad * 8;

    #pragma unroll
    for (int k = 0; k < K; k += 32) {
        short8 a  = *(const short8*)(Ap + k);
        short8 b0 = *(const short8*)(B0 + k);
        short8 b1 = *(const short8*)(B1 + k);
        short8 b2 = *(const short8*)(B2 + k);
        short8 b3 = *(const short8*)(B3 + k);
        acc0 = __builtin_amdgcn_mfma_f32_16x16x32_bf16(a, b0, acc0, 0, 0, 0);
        acc1 = __builtin_amdgcn_mfma_f32_16x16x32_bf16(a, b1, acc1, 0, 0, 0);
        acc2 = __builtin_amdgcn_mfma_f32_16x16x32_bf16(a, b2, acc2, 0, 0, 0);
        acc3 = __builtin_amdgcn_mfma_f32_16x16x32_bf16(a, b3, acc3, 0, 0, 0);
    }

    unsigned short* Cp = C + (size_t)(m0 + quad * 4) * HDIM + n0 + l15;
    #pragma unroll
    for (int r = 0; r < 4; ++r) {
        Cp[(size_t)r * HDIM +  0] = f2bu(acc0[r]);
        Cp[(size_t)r * HDIM + 16] = f2bu(acc1[r]);
        Cp[(size_t)r * HDIM + 32] = f2bu(acc2[r]);
        Cp[(size_t)r * HDIM + 48] = f2bu(acc3[r]);
    }
}

// ---------------- Aggregation: one wave per dst node, bf16 rows ----------------
// out[n] = relu( sum_e coef_e * h[src_e] + dinv[n]^2 * h[n] + bias ), bf16 in/out,
// fp32 accumulate. Edge loop unrolled x4 -> 4 gathers in flight.

__global__ __launch_bounds__(256) void k_agg(const unsigned short* __restrict__ hb,
                                             const float* __restrict__ dinv,
                                             const int* __restrict__ row_ptr,
                                             const int2* __restrict__ csr,
                                             const float* __restrict__ bias,
                                             unsigned short* __restrict__ outb, int N) {
    int wave = threadIdx.x >> 6, lane = threadIdx.x & 63;
    int n = blockIdx.x * 4 + wave;
    if (n >= N) return;
    float dn = dinv[n];
    int beg = row_ptr[n], end = row_ptr[n + 1];
    int col = lane * 4;
    float ax = 0.f, ay = 0.f, az = 0.f, aw = 0.f;

    int j = beg;
    for (; j + 4 <= end; j += 4) {
        int2 p0 = csr[j], p1 = csr[j+1], p2 = csr[j+2], p3 = csr[j+3];
        ushort4 v0 = *(const ushort4*)(hb + (size_t)p0.x * HDIM + col);
        ushort4 v1 = *(const ushort4*)(hb + (size_t)p1.x * HDIM + col);
        ushort4 v2 = *(const ushort4*)(hb + (size_t)p2.x * HDIM + col);
        ushort4 v3 = *(const ushort4*)(hb + (size_t)p3.x * HDIM + col);
        float c0 = __int_as_float(p0.y), c1 = __int_as_float(p1.y);
        float c2 = __int_as_float(p2.y), c3 = __int_as_float(p3.y);
        ax = fmaf(c0, b2f(v0.x), ax); ay = fmaf(c0, b2f(v0.y), ay);
        az = fmaf(c0, b2f(v0.z), az); aw = fmaf(c0, b2f(v0.w), aw);
        ax = fmaf(c1, b2f(v1.x), ax); ay = fmaf(c1, b2f(v1.y), ay);
        az = fmaf(c1, b2f(v1.z), az); aw = fmaf(c1, b2f(v1.w), aw);
        ax = fmaf(c2, b2f(v2.x), ax); ay = fmaf(c2, b2f(v2.y), ay);
        az = fmaf(c2, b2f(v2.z), az); aw = fmaf(c2, b2f(v2.w), aw);
        ax = fmaf(c3, b2f(v3.x), ax); ay = fmaf(c3, b2f(v3.y), ay);
        az = fmaf(c3, b2f(v3.z), az); aw = fmaf(c3, b2f(v3.w), aw);
    }
    for (; j < end; ++j) {
        int2 p = csr[j];
        ushort4 v = *(const ushort4*)(hb + (size_t)p.x * HDIM + col);
        float c = __int_as_float(p.y);
        ax = fmaf(c, b2f(v.x), ax); ay = fmaf(c, b2f(v.y), ay);
        az = fmaf(c, b2f(v.z), az); aw = fmaf(c, b2f(v.w), aw);
    }

    ushort4 sv = *(const ushort4*)(hb + (size_t)n * HDIM + col);
    const float4 b4 = *(const float4*)(bias + col);
    float sc = dn * dn;
    float r0 = fmaxf(fmaf(sc, b2f(sv.x), ax) + b4.x, 0.f);
    float r1 = fmaxf(fmaf(sc, b2f(sv.y), ay) + b4.y, 0.f);
    float r2 = fmaxf(fmaf(sc, b2f(sv.z), az) + b4.z, 0.f);
    float r3 = fmaxf(fmaf(sc, b2f(sv.w), aw) + b4.w, 0.f);
    ushort4 p;
    p.x = f2bu(r0); p.y = f2bu(r1); p.z = f2bu(r2); p.w = f2bu(r3);
    *(ushort4*)(outb + (size_t)n * HDIM + col) = p;
}

// ---------------- mean-pool partials + final linear ----------------

__global__ void k_colsum(const unsigned short* __restrict__ h2, float* __restrict__ gsum, int N) {
    int c = threadIdx.x;  // 256
    float acc = 0.f;
    for (int r = blockIdx.x; r < N; r += gridDim.x)
        acc += b2f(h2[(size_t)r * HDIM + c]);
    atomicAdd(&gsum[c], acc);
}

__global__ void k_final(const float* __restrict__ gsum, const float* __restrict__ Wl,
                        const float* __restrict__ bl, float* __restrict__ out, float invN) {
    __shared__ float s0[256], s1[256];
    int c = threadIdx.x;
    float g = gsum[c] * invN;
    s0[c] = g * Wl[c * 2 + 0];
    s1[c] = g * Wl[c * 2 + 1];
    __syncthreads();
    for (int off = 128; off > 0; off >>= 1) {
        if (c < off) { s0[c] += s0[c + off]; s1[c] += s1[c + off]; }
        __syncthreads();
    }
    if (c == 0) { out[0] = s0[0] + bl[0]; out[1] = s1[0] + bl[1]; }
}

// ---------------- launch ----------------

extern "C" void kernel_launch(void* const* d_in, const int* in_sizes, int n_in,
                              void* d_out, int out_size, void* d_ws, size_t ws_size,
                              hipStream_t stream) {
    const float* x  = (const float*)d_in[0];
    const int*   ei = (const int*)d_in[1];
    const float* W1 = (const float*)d_in[3];
    const float* b1 = (const float*)d_in[4];
    const float* W2 = (const float*)d_in[5];
    const float* b2 = (const float*)d_in[6];
    const float* Wl = (const float*)d_in[7];
    const float* bl = (const float*)d_in[8];
    float* out = (float*)d_out;

    const int N = in_sizes[0] / FIN;   // 50000
    const int E = in_sizes[1] / 2;     // 800000
    const int* src = ei;
    const int* dst = ei + E;
    const int NB = (N + 255) / 256;    // 196 scan blocks

    char* ws = (char*)d_ws;
    size_t off = 0;
    auto alloc = [&](size_t bytes) -> void* {
        void* p = ws + off;
        off = (off + bytes + 255) & ~(size_t)255;
        return p;
    };
    int*   deg     = (int*)  alloc((size_t)N * 4);
    float* dinv    = (float*)alloc((size_t)N * 4);
    int*   row_ptr = (int*)  alloc((size_t)(N + 1) * 4);
    int*   cursor  = (int*)  alloc((size_t)N * 4);
    int*   bsum    = (int*)  alloc(256 * 4);
    int*   boff    = (int*)  alloc(256 * 4);
    int2*  csr     = (int2*) alloc((size_t)E * 8);
    unsigned short* Xb   = (unsigned short*)alloc((size_t)N * FIN * 2);
    unsigned short* W1T  = (unsigned short*)alloc((size_t)FIN * HDIM * 2);
    unsigned short* W2T  = (unsigned short*)alloc((size_t)HDIM * HDIM * 2);
    unsigned short* hlin = (unsigned short*)alloc((size_t)N * HDIM * 2);  // GEMM out (both layers)
    unsigned short* h1b  = (unsigned short*)alloc((size_t)N * HDIM * 2);  // agg1 out
    unsigned short* h2b  = (unsigned short*)alloc((size_t)N * HDIM * 2);  // agg2 out
    float* gsum    = (float*)alloc((size_t)HDIM * 4);

    hipMemsetAsync(deg, 0, (size_t)N * 4, stream);
    hipMemsetAsync(gsum, 0, (size_t)HDIM * 4, stream);

    // CSR build (by dst)
    k_count   <<<(E + 255) / 256, 256, 0, stream>>>(dst, deg, E);
    k_blocksum<<<NB, 256, 0, stream>>>(deg, bsum, N);
    k_scanb   <<<1, 256, 0, stream>>>(bsum, boff, NB);
    k_scatter <<<NB, 256, 0, stream>>>(deg, boff, row_ptr, cursor, dinv, N, E);
    k_fill    <<<(E + 255) / 256, 256, 0, stream>>>(src, dst, dinv, cursor, csr, E);

    // bf16 casts
    k_cvt   <<<((size_t)N * FIN + 255) / 256, 256, 0, stream>>>(x, Xb, N * FIN);
    k_cvt_wT<<<(FIN * HDIM + 255) / 256, 256, 0, stream>>>(W1, W1T, FIN, HDIM);
    k_cvt_wT<<<(HDIM * HDIM + 255) / 256, 256, 0, stream>>>(W2, W2T, HDIM, HDIM);

    dim3 gemm_grid((N / 16 + 3) / 4, HDIM / 64);

    // layer 1
    k_gemm<FIN> <<<gemm_grid, 256, 0, stream>>>(Xb, W1T, hlin, N);
    k_agg       <<<(N + 3) / 4, 256, 0, stream>>>(hlin, dinv, row_ptr, csr, b1, h1b, N);

    // layer 2
    k_gemm<HDIM><<<gemm_grid, 256, 0, stream>>>(h1b, W2T, hlin, N);
    k_agg       <<<(N + 3) / 4, 256, 0, stream>>>(hlin, dinv, row_ptr, csr, b2, h2b, N);

    // mean-pool + final linear
    k_colsum<<<256, 256, 0, stream>>>(h2b, gsum, N);
    k_final <<<1, 256, 0, stream>>>(gsum, Wl, bl, out, 1.0f / (float)N);
}

// Round 3
// 403.131 us; speedup vs baseline: 1.8051x; 1.1121x over previous
//
#include <hip/hip_runtime.h>
#include <hip/hip_bf16.h>

#define FIN  128
#define HDIM 256

using bf16 = __hip_bfloat16;
using short8 = __attribute__((ext_vector_type(8))) short;
using f32x4  = __attribute__((ext_vector_type(4))) float;

static __device__ __forceinline__ unsigned short f2bu(float f) {
    bf16 t = __float2bfloat16(f);
    return *(unsigned short*)&t;
}
static __device__ __forceinline__ float b2f(unsigned short u) {
    return __uint_as_float(((unsigned)u) << 16);
}

// ---------------- CSR build ----------------

__global__ void k_count(const int* __restrict__ dst, int* __restrict__ deg, int E) {
    int e = blockIdx.x * blockDim.x + threadIdx.x;
    if (e < E) atomicAdd(&deg[dst[e]], 1);
}

__global__ void k_blocksum(const int* __restrict__ deg, int* __restrict__ bsum, int N) {
    __shared__ int s[256];
    int t = threadIdx.x;
    int i = blockIdx.x * 256 + t;
    s[t] = (i < N) ? deg[i] : 0;
    __syncthreads();
    for (int off = 128; off > 0; off >>= 1) {
        if (t < off) s[t] += s[t + off];
        __syncthreads();
    }
    if (t == 0) bsum[blockIdx.x] = s[0];
}

__global__ void k_scanb(const int* __restrict__ bsum, int* __restrict__ boff, int NB) {
    __shared__ int s[256];
    int t = threadIdx.x;
    int v = (t < NB) ? bsum[t] : 0;
    s[t] = v;
    __syncthreads();
    for (int off = 1; off < 256; off <<= 1) {
        int u = (t >= off) ? s[t - off] : 0;
        __syncthreads();
        s[t] += u;
        __syncthreads();
    }
    if (t < NB) boff[t] = s[t] - v;
}

__global__ void k_scatter(const int* __restrict__ deg, const int* __restrict__ boff,
                          int* __restrict__ row_ptr, int* __restrict__ cursor,
                          float* __restrict__ dinv, int N, int E) {
    __shared__ int s[256];
    int t = threadIdx.x;
    int i = blockIdx.x * 256 + t;
    int v = (i < N) ? deg[i] : 0;
    s[t] = v;
    __syncthreads();
    for (int off = 1; off < 256; off <<= 1) {
        int u = (t >= off) ? s[t - off] : 0;
        __syncthreads();
        s[t] += u;
        __syncthreads();
    }
    if (i < N) {
        int excl = boff[blockIdx.x] + s[t] - v;
        row_ptr[i] = excl;
        cursor[i]  = excl;
        dinv[i]    = rsqrtf((float)v + 1.0f);
    }
    if (blockIdx.x == 0 && t == 0) row_ptr[N] = E;
}

__global__ void k_fill(const int* __restrict__ src, const int* __restrict__ dst,
                       const float* __restrict__ dinv,
                       int* __restrict__ cursor, int2* __restrict__ csr, int E) {
    int e = blockIdx.x * blockDim.x + threadIdx.x;
    if (e < E) {
        int s = src[e], d = dst[e];
        int pos = atomicAdd(&cursor[d], 1);
        float c = dinv[s] * dinv[d];
        csr[pos] = make_int2(s, __float_as_int(c));
    }
}

// ---------------- weight transpose+cast: w[K][C] -> wT[C][K] bf16 ----------------

__global__ void k_cvt_wT(const float* __restrict__ w, unsigned short* __restrict__ wT, int K, int C) {
    int i = blockIdx.x * blockDim.x + threadIdx.x;
    if (i < K * C) {
        int k = i / C, c = i % C;
        wT[c * K + k] = f2bu(w[i]);
    }
}

// ---------------- GEMM: C[M,256](bf16) = A[M,K] * B[K,256] ----------------
// BT = B^T [256][K] bf16. Block: 64-col slice of B staged in LDS (padded, 16B-aligned),
// 4 waves x 4 row-tiles each, A-frags streamed from global (CVT: fp32->bf16 in-reg).
// grid.x = col-block (4) -> adjacent blocks share A rows through L2/L3.
// C/D layout: col=lane&15, row=quad*4+reg.

template <int K, bool CVT>
__global__ __launch_bounds__(256, 4) void k_gemm(const void* __restrict__ Av,
                                                 const unsigned short* __restrict__ BT,
                                                 unsigned short* __restrict__ C, int M) {
    constexpr int KP = K + 8;                       // +16B pad: lane stride 4 banks, 2-way max
    __shared__ __align__(16) unsigned short Bs[64 * KP];
    int tid = threadIdx.x;
    int wave = tid >> 6, lane = tid & 63;
    int n0 = blockIdx.x * 64;
    int tileBase = blockIdx.y * 16;

    constexpr int CH = 64 * (K / 8);
    for (int c = tid; c < CH; c += 256) {
        int r = c / (K / 8), kk = (c % (K / 8)) * 8;
        *(short8*)&Bs[r * KP + kk] = *(const short8*)(BT + (size_t)(n0 + r) * K + kk);
    }
    __syncthreads();

    int l15 = lane & 15, quad = lane >> 4;

    #pragma unroll
    for (int i = 0; i < 4; ++i) {
        int rt = tileBase + i * 4 + wave;
        if (rt * 16 >= M) continue;
        int m0 = rt * 16;

        short8 af[K / 32];
        if constexpr (CVT) {
            const float* Ap = (const float*)Av + (size_t)(m0 + l15) * K + quad * 8;
            #pragma unroll
            for (int ks = 0; ks < K / 32; ++ks) {
                float4 lo = *(const float4*)(Ap + ks * 32);
                float4 hi = *(const float4*)(Ap + ks * 32 + 4);
                short8 a;
                a[0] = (short)f2bu(lo.x); a[1] = (short)f2bu(lo.y);
                a[2] = (short)f2bu(lo.z); a[3] = (short)f2bu(lo.w);
                a[4] = (short)f2bu(hi.x); a[5] = (short)f2bu(hi.y);
                a[6] = (short)f2bu(hi.z); a[7] = (short)f2bu(hi.w);
                af[ks] = a;
            }
        } else {
            const unsigned short* Ap = (const unsigned short*)Av + (size_t)(m0 + l15) * K + quad * 8;
            #pragma unroll
            for (int ks = 0; ks < K / 32; ++ks)
                af[ks] = *(const short8*)(Ap + ks * 32);
        }

        f32x4 acc0 = {0.f,0.f,0.f,0.f}, acc1 = {0.f,0.f,0.f,0.f};
        f32x4 acc2 = {0.f,0.f,0.f,0.f}, acc3 = {0.f,0.f,0.f,0.f};
        #pragma unroll
        for (int ks = 0; ks < K / 32; ++ks) {
            int kk = ks * 32 + quad * 8;
            short8 b0 = *(const short8*)&Bs[(l15 +  0) * KP + kk];
            short8 b1 = *(const short8*)&Bs[(l15 + 16) * KP + kk];
            short8 b2 = *(const short8*)&Bs[(l15 + 32) * KP + kk];
            short8 b3 = *(const short8*)&Bs[(l15 + 48) * KP + kk];
            acc0 = __builtin_amdgcn_mfma_f32_16x16x32_bf16(af[ks], b0, acc0, 0, 0, 0);
            acc1 = __builtin_amdgcn_mfma_f32_16x16x32_bf16(af[ks], b1, acc1, 0, 0, 0);
            acc2 = __builtin_amdgcn_mfma_f32_16x16x32_bf16(af[ks], b2, acc2, 0, 0, 0);
            acc3 = __builtin_amdgcn_mfma_f32_16x16x32_bf16(af[ks], b3, acc3, 0, 0, 0);
        }

        unsigned short* Cp = C + (size_t)(m0 + quad * 4) * HDIM + n0 + l15;
        #pragma unroll
        for (int r = 0; r < 4; ++r) {
            Cp[(size_t)r * HDIM +  0] = f2bu(acc0[r]);
            Cp[(size_t)r * HDIM + 16] = f2bu(acc1[r]);
            Cp[(size_t)r * HDIM + 32] = f2bu(acc2[r]);
            Cp[(size_t)r * HDIM + 48] = f2bu(acc3[r]);
        }
    }
}

// ---------------- Aggregation layer 1: one wave per dst node ----------------

__global__ __launch_bounds__(256) void k_agg(const unsigned short* __restrict__ hb,
                                             const float* __restrict__ dinv,
                                             const int* __restrict__ row_ptr,
                                             const int2* __restrict__ csr,
                                             const float* __restrict__ bias,
                                             unsigned short* __restrict__ outb, int N) {
    int wave = threadIdx.x >> 6, lane = threadIdx.x & 63;
    int n = blockIdx.x * 4 + wave;
    if (n >= N) return;
    float dn = dinv[n];
    int beg = row_ptr[n], end = row_ptr[n + 1];
    int col = lane * 4;
    float ax = 0.f, ay = 0.f, az = 0.f, aw = 0.f;

    int j = beg;
    for (; j + 4 <= end; j += 4) {
        int2 p0 = csr[j], p1 = csr[j+1], p2 = csr[j+2], p3 = csr[j+3];
        ushort4 v0 = *(const ushort4*)(hb + (size_t)p0.x * HDIM + col);
        ushort4 v1 = *(const ushort4*)(hb + (size_t)p1.x * HDIM + col);
        ushort4 v2 = *(const ushort4*)(hb + (size_t)p2.x * HDIM + col);
        ushort4 v3 = *(const ushort4*)(hb + (size_t)p3.x * HDIM + col);
        float c0 = __int_as_float(p0.y), c1 = __int_as_float(p1.y);
        float c2 = __int_as_float(p2.y), c3 = __int_as_float(p3.y);
        ax = fmaf(c0, b2f(v0.x), ax); ay = fmaf(c0, b2f(v0.y), ay);
        az = fmaf(c0, b2f(v0.z), az); aw = fmaf(c0, b2f(v0.w), aw);
        ax = fmaf(c1, b2f(v1.x), ax); ay = fmaf(c1, b2f(v1.y), ay);
        az = fmaf(c1, b2f(v1.z), az); aw = fmaf(c1, b2f(v1.w), aw);
        ax = fmaf(c2, b2f(v2.x), ax); ay = fmaf(c2, b2f(v2.y), ay);
        az = fmaf(c2, b2f(v2.z), az); aw = fmaf(c2, b2f(v2.w), aw);
        ax = fmaf(c3, b2f(v3.x), ax); ay = fmaf(c3, b2f(v3.y), ay);
        az = fmaf(c3, b2f(v3.z), az); aw = fmaf(c3, b2f(v3.w), aw);
    }
    for (; j < end; ++j) {
        int2 p = csr[j];
        ushort4 v = *(const ushort4*)(hb + (size_t)p.x * HDIM + col);
        float c = __int_as_float(p.y);
        ax = fmaf(c, b2f(v.x), ax); ay = fmaf(c, b2f(v.y), ay);
        az = fmaf(c, b2f(v.z), az); aw = fmaf(c, b2f(v.w), aw);
    }

    ushort4 sv = *(const ushort4*)(hb + (size_t)n * HDIM + col);
    const float4 b4 = *(const float4*)(bias + col);
    float sc = dn * dn;
    ushort4 p;
    p.x = f2bu(fmaxf(fmaf(sc, b2f(sv.x), ax) + b4.x, 0.f));
    p.y = f2bu(fmaxf(fmaf(sc, b2f(sv.y), ay) + b4.y, 0.f));
    p.z = f2bu(fmaxf(fmaf(sc, b2f(sv.z), az) + b4.z, 0.f));
    p.w = f2bu(fmaxf(fmaf(sc, b2f(sv.w), aw) + b4.w, 0.f));
    *(ushort4*)(outb + (size_t)n * HDIM + col) = p;
}

// ---------------- Aggregation layer 2 + fused column-sum ----------------
// 16 nodes/block (4 waves x 4 sequential nodes). No h2 materialization: per-block
// LDS reduce -> 256 atomicAdds into gsum (3125-deep chains spread over the kernel).

__global__ __launch_bounds__(256) void k_agg_sum(const unsigned short* __restrict__ hb,
                                                 const float* __restrict__ dinv,
                                                 const int* __restrict__ row_ptr,
                                                 const int2* __restrict__ csr,
                                                 const float* __restrict__ bias,
                                                 float* __restrict__ gsum, int N) {
    __shared__ float gs[4][256];
    int wave = threadIdx.x >> 6, lane = threadIdx.x & 63;
    int col = lane * 4;
    const float4 b4 = *(const float4*)(bias + col);

    float cs0 = 0.f, cs1 = 0.f, cs2 = 0.f, cs3 = 0.f;
    for (int i = 0; i < 4; ++i) {
        int n = blockIdx.x * 16 + i * 4 + wave;
        if (n >= N) break;
        float dn = dinv[n];
        int beg = row_ptr[n], end = row_ptr[n + 1];
        float ax = 0.f, ay = 0.f, az = 0.f, aw = 0.f;
        int j = beg;
        for (; j + 4 <= end; j += 4) {
            int2 p0 = csr[j], p1 = csr[j+1], p2 = csr[j+2], p3 = csr[j+3];
            ushort4 v0 = *(const ushort4*)(hb + (size_t)p0.x * HDIM + col);
            ushort4 v1 = *(const ushort4*)(hb + (size_t)p1.x * HDIM + col);
            ushort4 v2 = *(const ushort4*)(hb + (size_t)p2.x * HDIM + col);
            ushort4 v3 = *(const ushort4*)(hb + (size_t)p3.x * HDIM + col);
            float c0 = __int_as_float(p0.y), c1 = __int_as_float(p1.y);
            float c2 = __int_as_float(p2.y), c3 = __int_as_float(p3.y);
            ax = fmaf(c0, b2f(v0.x), ax); ay = fmaf(c0, b2f(v0.y), ay);
            az = fmaf(c0, b2f(v0.z), az); aw = fmaf(c0, b2f(v0.w), aw);
            ax = fmaf(c1, b2f(v1.x), ax); ay = fmaf(c1, b2f(v1.y), ay);
            az = fmaf(c1, b2f(v1.z), az); aw = fmaf(c1, b2f(v1.w), aw);
            ax = fmaf(c2, b2f(v2.x), ax); ay = fmaf(c2, b2f(v2.y), ay);
            az = fmaf(c2, b2f(v2.z), az); aw = fmaf(c2, b2f(v2.w), aw);
            ax = fmaf(c3, b2f(v3.x), ax); ay = fmaf(c3, b2f(v3.y), ay);
            az = fmaf(c3, b2f(v3.z), az); aw = fmaf(c3, b2f(v3.w), aw);
        }
        for (; j < end; ++j) {
            int2 p = csr[j];
            ushort4 v = *(const ushort4*)(hb + (size_t)p.x * HDIM + col);
            float c = __int_as_float(p.y);
            ax = fmaf(c, b2f(v.x), ax); ay = fmaf(c, b2f(v.y), ay);
            az = fmaf(c, b2f(v.z), az); aw = fmaf(c, b2f(v.w), aw);
        }
        ushort4 sv = *(const ushort4*)(hb + (size_t)n * HDIM + col);
        float sc = dn * dn;
        cs0 += fmaxf(fmaf(sc, b2f(sv.x), ax) + b4.x, 0.f);
        cs1 += fmaxf(fmaf(sc, b2f(sv.y), ay) + b4.y, 0.f);
        cs2 += fmaxf(fmaf(sc, b2f(sv.z), az) + b4.z, 0.f);
        cs3 += fmaxf(fmaf(sc, b2f(sv.w), aw) + b4.w, 0.f);
    }
    gs[wave][col + 0] = cs0; gs[wave][col + 1] = cs1;
    gs[wave][col + 2] = cs2; gs[wave][col + 3] = cs3;
    __syncthreads();
    int t = threadIdx.x;
    float s = gs[0][t] + gs[1][t] + gs[2][t] + gs[3][t];
    atomicAdd(&gsum[t], s);
}

// ---------------- final linear on pooled vector ----------------

__global__ void k_final(const float* __restrict__ gsum, const float* __restrict__ Wl,
                        const float* __restrict__ bl, float* __restrict__ out, float invN) {
    __shared__ float s0[256], s1[256];
    int c = threadIdx.x;
    float g = gsum[c] * invN;
    s0[c] = g * Wl[c * 2 + 0];
    s1[c] = g * Wl[c * 2 + 1];
    __syncthreads();
    for (int off = 128; off > 0; off >>= 1) {
        if (c < off) { s0[c] += s0[c + off]; s1[c] += s1[c + off]; }
        __syncthreads();
    }
    if (c == 0) { out[0] = s0[0] + bl[0]; out[1] = s1[0] + bl[1]; }
}

// ---------------- launch ----------------

extern "C" void kernel_launch(void* const* d_in, const int* in_sizes, int n_in,
                              void* d_out, int out_size, void* d_ws, size_t ws_size,
                              hipStream_t stream) {
    const float* x  = (const float*)d_in[0];
    const int*   ei = (const int*)d_in[1];
    const float* W1 = (const float*)d_in[3];
    const float* b1 = (const float*)d_in[4];
    const float* W2 = (const float*)d_in[5];
    const float* b2 = (const float*)d_in[6];
    const float* Wl = (const float*)d_in[7];
    const float* bl = (const float*)d_in[8];
    float* out = (float*)d_out;

    const int N = in_sizes[0] / FIN;   // 50000
    const int E = in_sizes[1] / 2;     // 800000
    const int* src = ei;
    const int* dst = ei + E;
    const int NB = (N + 255) / 256;

    char* ws = (char*)d_ws;
    size_t off = 0;
    auto alloc = [&](size_t bytes) -> void* {
        void* p = ws + off;
        off = (off + bytes + 255) & ~(size_t)255;
        return p;
    };
    int*   deg     = (int*)  alloc((size_t)N * 4);
    float* dinv    = (float*)alloc((size_t)N * 4);
    int*   row_ptr = (int*)  alloc((size_t)(N + 1) * 4);
    int*   cursor  = (int*)  alloc((size_t)N * 4);
    int*   bsum    = (int*)  alloc(256 * 4);
    int*   boff    = (int*)  alloc(256 * 4);
    int2*  csr     = (int2*) alloc((size_t)E * 8);
    unsigned short* W1T  = (unsigned short*)alloc((size_t)FIN * HDIM * 2);
    unsigned short* W2T  = (unsigned short*)alloc((size_t)HDIM * HDIM * 2);
    unsigned short* hlin = (unsigned short*)alloc((size_t)N * HDIM * 2);  // GEMM out (both layers)
    unsigned short* h1b  = (unsigned short*)alloc((size_t)N * HDIM * 2);  // agg1 out
    float* gsum    = (float*)alloc((size_t)HDIM * 4);

    hipMemsetAsync(deg, 0, (size_t)N * 4, stream);
    hipMemsetAsync(gsum, 0, (size_t)HDIM * 4, stream);

    // CSR build (by dst)
    k_count   <<<(E + 255) / 256, 256, 0, stream>>>(dst, deg, E);
    k_blocksum<<<NB, 256, 0, stream>>>(deg, bsum, N);
    k_scanb   <<<1, 256, 0, stream>>>(bsum, boff, NB);
    k_scatter <<<NB, 256, 0, stream>>>(deg, boff, row_ptr, cursor, dinv, N, E);
    k_fill    <<<(E + 255) / 256, 256, 0, stream>>>(src, dst, dinv, cursor, csr, E);

    // weight casts
    k_cvt_wT<<<(FIN * HDIM + 255) / 256, 256, 0, stream>>>(W1, W1T, FIN, HDIM);
    k_cvt_wT<<<(HDIM * HDIM + 255) / 256, 256, 0, stream>>>(W2, W2T, HDIM, HDIM);

    const int tiles = (N + 15) / 16;            // 3125 row tiles
    dim3 gemm_grid(HDIM / 64, (tiles + 15) / 16);

    // layer 1 (A = x fp32, converted in-register)
    k_gemm<FIN, true>  <<<gemm_grid, 256, 0, stream>>>(x, W1T, hlin, N);
    k_agg              <<<(N + 3) / 4, 256, 0, stream>>>(hlin, dinv, row_ptr, csr, b1, h1b, N);

    // layer 2
    k_gemm<HDIM, false><<<gemm_grid, 256, 0, stream>>>(h1b, W2T, hlin, N);
    k_agg_sum          <<<(N + 15) / 16, 256, 0, stream>>>(hlin, dinv, row_ptr, csr, b2, gsum, N);

    // final linear
    k_final<<<1, 256, 0, stream>>>(gsum, Wl, bl, out, 1.0f / (float)N);
}

// Round 4
// 349.034 us; speedup vs baseline: 2.0848x; 1.1550x over previous
//
#include <hip/hip_runtime.h>
#include <hip/hip_bf16.h>

#define FIN  128
#define HDIM 256

using bf16 = __hip_bfloat16;
using short8 = __attribute__((ext_vector_type(8))) short;
using u16x8  = __attribute__((ext_vector_type(8))) unsigned short;
using f32x4  = __attribute__((ext_vector_type(4))) float;

static __device__ __forceinline__ unsigned short f2bu(float f) {
    bf16 t = __float2bfloat16(f);
    return *(unsigned short*)&t;
}
static __device__ __forceinline__ float b2f(unsigned short u) {
    return __uint_as_float(((unsigned)u) << 16);
}

// ---------------- CSR build ----------------

__global__ void k_count(const int* __restrict__ dst, int* __restrict__ deg, int E) {
    int e = blockIdx.x * blockDim.x + threadIdx.x;
    if (e < E) atomicAdd(&deg[dst[e]], 1);
}

__global__ void k_blocksum(const int* __restrict__ deg, int* __restrict__ bsum, int N) {
    __shared__ int s[256];
    int t = threadIdx.x;
    int i = blockIdx.x * 256 + t;
    s[t] = (i < N) ? deg[i] : 0;
    __syncthreads();
    for (int off = 128; off > 0; off >>= 1) {
        if (t < off) s[t] += s[t + off];
        __syncthreads();
    }
    if (t == 0) bsum[blockIdx.x] = s[0];
}

__global__ void k_scanb(const int* __restrict__ bsum, int* __restrict__ boff, int NB) {
    __shared__ int s[256];
    int t = threadIdx.x;
    int v = (t < NB) ? bsum[t] : 0;
    s[t] = v;
    __syncthreads();
    for (int off = 1; off < 256; off <<= 1) {
        int u = (t >= off) ? s[t - off] : 0;
        __syncthreads();
        s[t] += u;
        __syncthreads();
    }
    if (t < NB) boff[t] = s[t] - v;
}

__global__ void k_scatter(const int* __restrict__ deg, const int* __restrict__ boff,
                          int* __restrict__ row_ptr, int* __restrict__ cursor,
                          float* __restrict__ dinv, int N, int E) {
    __shared__ int s[256];
    int t = threadIdx.x;
    int i = blockIdx.x * 256 + t;
    int v = (i < N) ? deg[i] : 0;
    s[t] = v;
    __syncthreads();
    for (int off = 1; off < 256; off <<= 1) {
        int u = (t >= off) ? s[t - off] : 0;
        __syncthreads();
        s[t] += u;
        __syncthreads();
    }
    if (i < N) {
        int excl = boff[blockIdx.x] + s[t] - v;
        row_ptr[i] = excl;
        cursor[i]  = excl;
        dinv[i]    = rsqrtf((float)v + 1.0f);
    }
    if (blockIdx.x == 0 && t == 0) row_ptr[N] = E;
}

__global__ void k_fill(const int* __restrict__ src, const int* __restrict__ dst,
                       const float* __restrict__ dinv,
                       int* __restrict__ cursor, int2* __restrict__ csr, int E) {
    int e = blockIdx.x * blockDim.x + threadIdx.x;
    if (e < E) {
        int s = src[e], d = dst[e];
        int pos = atomicAdd(&cursor[d], 1);
        float c = dinv[s] * dinv[d];
        csr[pos] = make_int2(s, __float_as_int(c));
    }
}

// ---------------- weight transpose+cast: w[K][C] -> wT[C][K] bf16 ----------------

__global__ void k_cvt_wT(const float* __restrict__ w, unsigned short* __restrict__ wT, int K, int C) {
    int i = blockIdx.x * blockDim.x + threadIdx.x;
    if (i < K * C) {
        int k = i / C, c = i % C;
        wT[c * K + k] = f2bu(w[i]);
    }
}

// ---------------- GEMM: C[M,256](bf16) = A[M,K] * B[K,256] ----------------
// BT = B^T [256][K] bf16. 64-col B slice staged in LDS; 4 waves x 4 row-tiles;
// A-frags streamed from global (CVT: fp32->bf16 in-reg). C/D: col=lane&15, row=quad*4+reg.

template <int K, bool CVT>
__global__ __launch_bounds__(256, 4) void k_gemm(const void* __restrict__ Av,
                                                 const unsigned short* __restrict__ BT,
                                                 unsigned short* __restrict__ C, int M) {
    constexpr int KP = K + 8;
    __shared__ __align__(16) unsigned short Bs[64 * KP];
    int tid = threadIdx.x;
    int wave = tid >> 6, lane = tid & 63;
    int n0 = blockIdx.x * 64;
    int tileBase = blockIdx.y * 16;

    constexpr int CH = 64 * (K / 8);
    for (int c = tid; c < CH; c += 256) {
        int r = c / (K / 8), kk = (c % (K / 8)) * 8;
        *(short8*)&Bs[r * KP + kk] = *(const short8*)(BT + (size_t)(n0 + r) * K + kk);
    }
    __syncthreads();

    int l15 = lane & 15, quad = lane >> 4;

    #pragma unroll
    for (int i = 0; i < 4; ++i) {
        int rt = tileBase + i * 4 + wave;
        if (rt * 16 >= M) continue;
        int m0 = rt * 16;

        short8 af[K / 32];
        if constexpr (CVT) {
            const float* Ap = (const float*)Av + (size_t)(m0 + l15) * K + quad * 8;
            #pragma unroll
            for (int ks = 0; ks < K / 32; ++ks) {
                float4 lo = *(const float4*)(Ap + ks * 32);
                float4 hi = *(const float4*)(Ap + ks * 32 + 4);
                short8 a;
                a[0] = (short)f2bu(lo.x); a[1] = (short)f2bu(lo.y);
                a[2] = (short)f2bu(lo.z); a[3] = (short)f2bu(lo.w);
                a[4] = (short)f2bu(hi.x); a[5] = (short)f2bu(hi.y);
                a[6] = (short)f2bu(hi.z); a[7] = (short)f2bu(hi.w);
                af[ks] = a;
            }
        } else {
            const unsigned short* Ap = (const unsigned short*)Av + (size_t)(m0 + l15) * K + quad * 8;
            #pragma unroll
            for (int ks = 0; ks < K / 32; ++ks)
                af[ks] = *(const short8*)(Ap + ks * 32);
        }

        f32x4 acc0 = {0.f,0.f,0.f,0.f}, acc1 = {0.f,0.f,0.f,0.f};
        f32x4 acc2 = {0.f,0.f,0.f,0.f}, acc3 = {0.f,0.f,0.f,0.f};
        #pragma unroll
        for (int ks = 0; ks < K / 32; ++ks) {
            int kk = ks * 32 + quad * 8;
            short8 b0 = *(const short8*)&Bs[(l15 +  0) * KP + kk];
            short8 b1 = *(const short8*)&Bs[(l15 + 16) * KP + kk];
            short8 b2 = *(const short8*)&Bs[(l15 + 32) * KP + kk];
            short8 b3 = *(const short8*)&Bs[(l15 + 48) * KP + kk];
            acc0 = __builtin_amdgcn_mfma_f32_16x16x32_bf16(af[ks], b0, acc0, 0, 0, 0);
            acc1 = __builtin_amdgcn_mfma_f32_16x16x32_bf16(af[ks], b1, acc1, 0, 0, 0);
            acc2 = __builtin_amdgcn_mfma_f32_16x16x32_bf16(af[ks], b2, acc2, 0, 0, 0);
            acc3 = __builtin_amdgcn_mfma_f32_16x16x32_bf16(af[ks], b3, acc3, 0, 0, 0);
        }

        unsigned short* Cp = C + (size_t)(m0 + quad * 4) * HDIM + n0 + l15;
        #pragma unroll
        for (int r = 0; r < 4; ++r) {
            Cp[(size_t)r * HDIM +  0] = f2bu(acc0[r]);
            Cp[(size_t)r * HDIM + 16] = f2bu(acc1[r]);
            Cp[(size_t)r * HDIM + 32] = f2bu(acc2[r]);
            Cp[(size_t)r * HDIM + 48] = f2bu(acc3[r]);
        }
    }
}

// ---------------- Aggregation: one wave per dst node, pair-gather ----------------
// Lanes 0-31 cover the 512B row of edge j, lanes 32-63 of edge j+1 (16B/lane).
// Halves combined once per node via __shfl_xor(...,32). Unroll: 4 loads = 8 edges
// in flight. STORE: write bf16 row. !STORE: fused column-sum -> block LDS reduce
// -> atomicAdd into 8 replicated gsum buffers (1563 adds/address).

template <bool STORE>
__global__ __launch_bounds__(256) void k_agg(const unsigned short* __restrict__ hb,
                                             const float* __restrict__ dinv,
                                             const int* __restrict__ row_ptr,
                                             const int2* __restrict__ csr,
                                             const float* __restrict__ bias,
                                             unsigned short* __restrict__ outb,
                                             float* __restrict__ gsum, int N) {
    __shared__ float gs[4][256];
    int wave = threadIdx.x >> 6, lane = threadIdx.x & 63;
    int half = lane >> 5, hl = lane & 31;
    int c0 = hl * 8;
    int n = blockIdx.x * 4 + wave;

    float r[8] = {0.f,0.f,0.f,0.f,0.f,0.f,0.f,0.f};

    if (n < N) {
        float acc[8] = {0.f,0.f,0.f,0.f,0.f,0.f,0.f,0.f};
        float dn = dinv[n];
        int beg = row_ptr[n], end = row_ptr[n + 1];
        int j = beg;
        for (; j + 8 <= end; j += 8) {
            int2 p0 = csr[j + 0 + half];
            int2 p1 = csr[j + 2 + half];
            int2 p2 = csr[j + 4 + half];
            int2 p3 = csr[j + 6 + half];
            u16x8 v0 = *(const u16x8*)(hb + (size_t)p0.x * HDIM + c0);
            u16x8 v1 = *(const u16x8*)(hb + (size_t)p1.x * HDIM + c0);
            u16x8 v2 = *(const u16x8*)(hb + (size_t)p2.x * HDIM + c0);
            u16x8 v3 = *(const u16x8*)(hb + (size_t)p3.x * HDIM + c0);
            float f0 = __int_as_float(p0.y), f1 = __int_as_float(p1.y);
            float f2 = __int_as_float(p2.y), f3 = __int_as_float(p3.y);
            #pragma unroll
            for (int k = 0; k < 8; ++k) acc[k] = fmaf(f0, b2f(v0[k]), acc[k]);
            #pragma unroll
            for (int k = 0; k < 8; ++k) acc[k] = fmaf(f1, b2f(v1[k]), acc[k]);
            #pragma unroll
            for (int k = 0; k < 8; ++k) acc[k] = fmaf(f2, b2f(v2[k]), acc[k]);
            #pragma unroll
            for (int k = 0; k < 8; ++k) acc[k] = fmaf(f3, b2f(v3[k]), acc[k]);
        }
        for (; j + 2 <= end; j += 2) {
            int2 p = csr[j + half];
            u16x8 v = *(const u16x8*)(hb + (size_t)p.x * HDIM + c0);
            float f = __int_as_float(p.y);
            #pragma unroll
            for (int k = 0; k < 8; ++k) acc[k] = fmaf(f, b2f(v[k]), acc[k]);
        }
        if (j < end) {                       // odd tail: half 1 contributes 0
            int2 p = csr[j];
            u16x8 v = *(const u16x8*)(hb + (size_t)p.x * HDIM + c0);
            float f = half ? 0.f : __int_as_float(p.y);
            #pragma unroll
            for (int k = 0; k < 8; ++k) acc[k] = fmaf(f, b2f(v[k]), acc[k]);
        }

        #pragma unroll
        for (int k = 0; k < 8; ++k) acc[k] += __shfl_xor(acc[k], 32, 64);

        u16x8 sv = *(const u16x8*)(hb + (size_t)n * HDIM + c0);
        float bb[8];
        *(float4*)&bb[0] = *(const float4*)(bias + c0);
        *(float4*)&bb[4] = *(const float4*)(bias + c0 + 4);
        float sc = dn * dn;
        #pragma unroll
        for (int k = 0; k < 8; ++k)
            r[k] = fmaxf(fmaf(sc, b2f(sv[k]), acc[k]) + bb[k], 0.f);

        if (STORE && half == 0) {
            u16x8 o;
            #pragma unroll
            for (int k = 0; k < 8; ++k) o[k] = f2bu(r[k]);
            *(u16x8*)(outb + (size_t)n * HDIM + c0) = o;
        }
    }

    if constexpr (!STORE) {
        if (half == 0) {
            #pragma unroll
            for (int k = 0; k < 8; ++k) gs[wave][c0 + k] = r[k];   // zeros if n>=N
        }
        __syncthreads();
        int t = threadIdx.x;
        float s = gs[0][t] + gs[1][t] + gs[2][t] + gs[3][t];
        atomicAdd(&gsum[((blockIdx.x & 7) << 8) + t], s);
    }
}

// ---------------- final linear on pooled vector (8 gsum replicas) ----------------

__global__ void k_final(const float* __restrict__ gsum, const float* __restrict__ Wl,
                        const float* __restrict__ bl, float* __restrict__ out, float invN) {
    __shared__ float s0[256], s1[256];
    int c = threadIdx.x;
    float g = 0.f;
    #pragma unroll
    for (int rp = 0; rp < 8; ++rp) g += gsum[rp * 256 + c];
    g *= invN;
    s0[c] = g * Wl[c * 2 + 0];
    s1[c] = g * Wl[c * 2 + 1];
    __syncthreads();
    for (int off = 128; off > 0; off >>= 1) {
        if (c < off) { s0[c] += s0[c + off]; s1[c] += s1[c + off]; }
        __syncthreads();
    }
    if (c == 0) { out[0] = s0[0] + bl[0]; out[1] = s1[0] + bl[1]; }
}

// ---------------- launch ----------------

extern "C" void kernel_launch(void* const* d_in, const int* in_sizes, int n_in,
                              void* d_out, int out_size, void* d_ws, size_t ws_size,
                              hipStream_t stream) {
    const float* x  = (const float*)d_in[0];
    const int*   ei = (const int*)d_in[1];
    const float* W1 = (const float*)d_in[3];
    const float* b1 = (const float*)d_in[4];
    const float* W2 = (const float*)d_in[5];
    const float* b2 = (const float*)d_in[6];
    const float* Wl = (const float*)d_in[7];
    const float* bl = (const float*)d_in[8];
    float* out = (float*)d_out;

    const int N = in_sizes[0] / FIN;   // 50000
    const int E = in_sizes[1] / 2;     // 800000
    const int* src = ei;
    const int* dst = ei + E;
    const int NB = (N + 255) / 256;

    char* ws = (char*)d_ws;
    size_t off = 0;
    auto alloc = [&](size_t bytes) -> void* {
        void* p = ws + off;
        off = (off + bytes + 255) & ~(size_t)255;
        return p;
    };
    int*   deg     = (int*)  alloc((size_t)N * 4);
    float* dinv    = (float*)alloc((size_t)N * 4);
    int*   row_ptr = (int*)  alloc((size_t)(N + 1) * 4);
    int*   cursor  = (int*)  alloc((size_t)N * 4);
    int*   bsum    = (int*)  alloc(256 * 4);
    int*   boff    = (int*)  alloc(256 * 4);
    int2*  csr     = (int2*) alloc((size_t)E * 8);
    unsigned short* W1T  = (unsigned short*)alloc((size_t)FIN * HDIM * 2);
    unsigned short* W2T  = (unsigned short*)alloc((size_t)HDIM * HDIM * 2);
    unsigned short* hlin = (unsigned short*)alloc((size_t)N * HDIM * 2);
    unsigned short* h1b  = (unsigned short*)alloc((size_t)N * HDIM * 2);
    float* gsum    = (float*)alloc((size_t)8 * HDIM * 4);

    hipMemsetAsync(deg, 0, (size_t)N * 4, stream);
    hipMemsetAsync(gsum, 0, (size_t)8 * HDIM * 4, stream);

    // CSR build (by dst)
    k_count   <<<(E + 255) / 256, 256, 0, stream>>>(dst, deg, E);
    k_blocksum<<<NB, 256, 0, stream>>>(deg, bsum, N);
    k_scanb   <<<1, 256, 0, stream>>>(bsum, boff, NB);
    k_scatter <<<NB, 256, 0, stream>>>(deg, boff, row_ptr, cursor, dinv, N, E);
    k_fill    <<<(E + 255) / 256, 256, 0, stream>>>(src, dst, dinv, cursor, csr, E);

    // weight casts
    k_cvt_wT<<<(FIN * HDIM + 255) / 256, 256, 0, stream>>>(W1, W1T, FIN, HDIM);
    k_cvt_wT<<<(HDIM * HDIM + 255) / 256, 256, 0, stream>>>(W2, W2T, HDIM, HDIM);

    const int tiles = (N + 15) / 16;
    dim3 gemm_grid(HDIM / 64, (tiles + 15) / 16);

    // layer 1 (A = x fp32, converted in-register)
    k_gemm<FIN, true>  <<<gemm_grid, 256, 0, stream>>>(x, W1T, hlin, N);
    k_agg<true>        <<<(N + 3) / 4, 256, 0, stream>>>(hlin, dinv, row_ptr, csr, b1, h1b, nullptr, N);

    // layer 2 + fused mean-pool partials
    k_gemm<HDIM, false><<<gemm_grid, 256, 0, stream>>>(h1b, W2T, hlin, N);
    k_agg<false>       <<<(N + 3) / 4, 256, 0, stream>>>(hlin, dinv, row_ptr, csr, b2, nullptr, gsum, N);

    // final linear
    k_final<<<1, 256, 0, stream>>>(gsum, Wl, bl, out, 1.0f / (float)N);
}